// Round 17
// baseline (335.360 us; speedup 1.0000x reference)
//
#include <hip/hip_runtime.h>
#include <hip/hip_fp16.h>
#include <math.h>

#define N 6000
#define FIN 300
#define HID 128
#define NH 8
#define ALPHA 0.2f
#define NBR_CAP 512
#define KSPLIT 4
#define KPAD 384           // FIN padded to 3x128 for MFMA chunks
#define NWORDS 188         // ceil(6000/32) u32 bitmask words per row
#define NCH 94             // 6016/64 chunks

typedef unsigned short u16;
typedef unsigned int u32;
typedef short bf16x8 __attribute__((ext_vector_type(8)));
typedef float f32x4 __attribute__((ext_vector_type(4)));

static __device__ __forceinline__ u16 f2bf(float f) {
    u32 u = __float_as_uint(f);
    u32 r = (u + 0x7fff + ((u >> 16) & 1)) >> 16;   // round-to-nearest-even
    return (u16)r;
}
static __device__ __forceinline__ u16 f2h(float f) {
    return __half_as_ushort(__float2half(f));
}

// K0+K1 fused: blocks [0,6000) build neighbor lists; remaining blocks do
// bf16 prep (xb, WbT, WoT) and av GEMVs.
#define PREP_NBLK (6000 + 9000 + 1536 + 512 + 8)
__global__ void prep_all(const float* __restrict__ adj,
                         const float* __restrict__ x,
                         const float* __restrict__ W,
                         const float* __restrict__ W_out,
                         const float* __restrict__ a_heads,
                         u16* __restrict__ nbr, int* __restrict__ ncnt,
                         u16* __restrict__ xb,
                         u16* __restrict__ WbT,
                         u16* __restrict__ WoT,
                         float* __restrict__ av1, float* __restrict__ av2) {
    int bid = blockIdx.x, t = threadIdx.x;
    __shared__ u16 lbuf[4][256];
    __shared__ int wc[4];
    __shared__ float a1s[HID], a2s[HID];
    if (bid < 6000) {                       // ---- build_nbr (ascending)
        int n = bid;
        int lane = t & 63, w = t >> 6;
        const int seg = N / 4;              // 1500
        int start = w * seg, end = start + seg;
        const float* row = adj + (size_t)n * N;
        int cnt = 0;
        for (int base = start; base < end; base += 256) {
            int m0 = base + 4 * lane;
            float4 v = make_float4(0.f, 0.f, 0.f, 0.f);
            if (m0 < end) v = *(const float4*)(row + m0);
#pragma unroll
            for (int c = 0; c < 4; c++) {
                float vc = (c == 0) ? v.x : (c == 1) ? v.y : (c == 2) ? v.z : v.w;
                bool p = vc > 0.5f;
                unsigned long long mask = __ballot(p);
                if (p) {
                    int pos = cnt + __popcll(mask & ((1ull << lane) - 1ull));
                    if (pos < 256) lbuf[w][pos] = (u16)(m0 + c);
                }
                cnt += __popcll(mask);
            }
        }
        if (cnt > 256) cnt = 256;
        if (lane == 0) wc[w] = cnt;
        __syncthreads();
        int offset = 0;
        for (int i = 0; i < w; i++) offset += wc[i];
        for (int i = lane; i < cnt; i += 64) {
            int idx = offset + i;
            if (idx < NBR_CAP) nbr[(size_t)n * NBR_CAP + idx] = lbuf[w][i];
        }
        if (t == 0) {
            int total = wc[0] + wc[1] + wc[2] + wc[3];
            ncnt[n] = total < NBR_CAP ? total : NBR_CAP;
        }
    } else if (bid < 6000 + 9000) {         // xb[n][k], 6000x384
        int idx = (bid - 6000) * 256 + t;
        int n = idx / KPAD, k = idx - n * KPAD;
        xb[idx] = (k < FIN) ? f2bf(x[(size_t)n * FIN + k]) : (u16)0;
    } else if (bid < 6000 + 9000 + 1536) {  // WbT[h][c][k], 8x128x384
        int idx = (bid - 6000 - 9000) * 256 + t;
        int k = idx % KPAD;
        int c = (idx / KPAD) & 127;
        int h = idx / (KPAD * HID);
        WbT[idx] = (k < FIN) ? f2bf(W[((size_t)h * FIN + k) * HID + c]) : (u16)0;
    } else if (bid < 6000 + 9000 + 1536 + 512) {   // WoT[c][k], 128x1024
        int idx = (bid - 6000 - 9000 - 1536) * 256 + t;
        int k = idx & 1023, c = idx >> 10;
        WoT[idx] = f2bf(W_out[(size_t)k * HID + c]);
    } else {                                // av1/av2[h][0..320)
        int h = bid - (6000 + 9000 + 1536 + 512);
        if (t < HID) {
            a1s[t] = a_heads[(size_t)h * 2 * HID + t];
            a2s[t] = a_heads[(size_t)h * 2 * HID + HID + t];
        }
        __syncthreads();
        for (int f = t; f < 320; f += 256) {
            float s1 = 0.f, s2 = 0.f;
            if (f < FIN) {
                const float* wr = W + ((size_t)h * FIN + f) * HID;
#pragma unroll 4
                for (int o = 0; o < HID; o++) { s1 += wr[o] * a1s[o]; s2 += wr[o] * a2s[o]; }
            }
            av1[h * 320 + f] = s1;
            av2[h * 320 + f] = s2;
        }
    }
}

// K0b: dense bitmask from neighbor lists (4.5 MB, L2-resident).
__global__ void build_bitmask(const u16* __restrict__ nbr,
                              const int* __restrict__ ncnt,
                              u32* __restrict__ adjb) {
    int n = blockIdx.x, t = threadIdx.x;
    __shared__ u32 bm[NWORDS];
    if (t < NWORDS) bm[t] = 0;
    __syncthreads();
    int cnt = ncnt[n];
    const u16* lst = nbr + (size_t)n * NBR_CAP;
    for (int i = t; i < cnt; i += 256) {
        int m = lst[i];
        atomicOr(&bm[m >> 5], 1u << (m & 31));
    }
    __syncthreads();
    if (t < NWORDS) adjb[(size_t)n * NWORDS + t] = bm[t];
}

// K2: f1[h][n] = x[n]·av1[h], f2 likewise — fp32-exact logits.
__global__ void calc_f(const float* __restrict__ x,
                       const float* __restrict__ av1, const float* __restrict__ av2,
                       float* __restrict__ f1, float* __restrict__ f2) {
    int n = blockIdx.x, t = threadIdx.x;
    int lane = t & 63, w = t >> 6;
    __shared__ float xsh[320];
    for (int i = t; i < 320; i += 256)
        xsh[i] = (i < FIN) ? x[(size_t)n * FIN + i] : 0.f;
    __syncthreads();
#pragma unroll
    for (int hh = 0; hh < 2; hh++) {
        int h = 2 * w + hh;
        const float* a1 = av1 + h * 320;
        const float* a2 = av2 + h * 320;
        float s1 = 0.f, s2 = 0.f;
#pragma unroll
        for (int i = 0; i < 5; i++) {
            float xv = xsh[lane + 64 * i];
            s1 += xv * a1[lane + 64 * i];
            s2 += xv * a2[lane + 64 * i];
        }
        for (int d = 1; d <= 32; d <<= 1) { s1 += __shfl_xor(s1, d); s2 += __shfl_xor(s2, d); }
        if (lane == 0) { f1[h * N + n] = s1; f2[h * N + n] = s2; }
    }
}

// K3a: WhbT[h][c][m] = bf16( (xb @ WbT[h])^T ) — MFMA with swapped operand
// roles: A = WbT rows (c) from LDS, B = xb rows (m) from global.
// Output stores coalesced along m. Verified fragment/C-D pattern (R10-R15).
__global__ __launch_bounds__(256)
void gemm_whT_mfma(const u16* __restrict__ xb,
                   const u16* __restrict__ WbT,
                   u16* __restrict__ WhbT) {
    int n0 = blockIdx.x * 64;
    int h = blockIdx.y;
    int t = threadIdx.x;
    int lane = t & 63, wid = t >> 6;
    int l4 = lane >> 4, lr = lane & 15;

    __shared__ u16 Bt[128][128];         // WbT chunk [c][k], swizzled

    f32x4 acc[2][4];
#pragma unroll
    for (int rt = 0; rt < 2; rt++)
#pragma unroll
        for (int ctl = 0; ctl < 4; ctl++)
            acc[rt][ctl] = (f32x4){0.f, 0.f, 0.f, 0.f};

    for (int half = 0; half < 3; half++) {
        int kbeg = half * 128;
        {
            int c = t >> 1, sh = t & 1;
            const u16* src = WbT + ((size_t)h * HID + c) * KPAD + kbeg + sh * 64;
            int cx = (c & 7) << 3;
            uint4 v[8];
#pragma unroll
            for (int j = 0; j < 8; j++) v[j] = ((const uint4*)src)[j];
#pragma unroll
            for (int j = 0; j < 8; j++)
                *(uint4*)&Bt[c][(sh * 64 + 8 * j) ^ cx] = v[j];
        }
        __syncthreads();
#pragma unroll
        for (int kst = 0; kst < 4; kst++) {
            int kb = kst * 32 + 8 * l4;
            int axr = (lr & 7) << 3;
            bf16x8 a0 = *(const bf16x8*)&Bt[32 * wid + lr][kb ^ axr];
            bf16x8 a1 = *(const bf16x8*)&Bt[32 * wid + 16 + lr][kb ^ axr];
#pragma unroll
            for (int ctl = 0; ctl < 4; ctl++) {
                int m = n0 + 16 * ctl + lr;      // OOB reads land in ws (finite-guarded at store)
                bf16x8 b = *(const bf16x8*)(xb + (size_t)m * KPAD + kbeg + kb);
                acc[0][ctl] = __builtin_amdgcn_mfma_f32_16x16x32_bf16(a0, b, acc[0][ctl], 0, 0, 0);
                acc[1][ctl] = __builtin_amdgcn_mfma_f32_16x16x32_bf16(a1, b, acc[1][ctl], 0, 0, 0);
            }
        }
        __syncthreads();
    }
    // epilogue: row = c = 32wid+16rt+4l4+reg, col = m = n0+16ctl+lr
#pragma unroll
    for (int rt = 0; rt < 2; rt++) {
#pragma unroll
        for (int reg = 0; reg < 4; reg++) {
            int c = 32 * wid + 16 * rt + 4 * l4 + reg;
            u16* orow = WhbT + ((size_t)h * HID + c) * N;
#pragma unroll
            for (int ctl = 0; ctl < 4; ctl++) {
                int m = n0 + 16 * ctl + lr;
                if (m < N) orow[m] = f2bf(acc[rt][ctl][reg]);
            }
        }
    }
}

// K3: layer-1 dense-masked softmax + PV via MFMA.
// Block = (64-row tile, head). Dense P-build from bitmask + LDS f2 slice:
// w = exp(max(s, 0.2s)) * bit, s = f1[n]+f2[m] — no lists, no scatter.
__global__ __launch_bounds__(256)
void gat1_dense(const u16* __restrict__ WhbT,
                const float* __restrict__ f1, const float* __restrict__ f2,
                const u32* __restrict__ adjb,
                u16* __restrict__ hcatb) {
    int tile = blockIdx.x, h = blockIdx.y;
    int n0 = tile * 64;
    int t = threadIdx.x;
    int lane = t & 63, wid = t >> 6;
    int l4 = lane >> 4, lr = lane & 15;
    int r = t >> 2, q = t & 3;           // P-build role: row r, quarter q

    __shared__ float f2s[6016];
    __shared__ u16 P[64][64];            // swizzled (elem ^ (r&7)<<3)
    __shared__ u16 Bt[128][64];          // swizzled (elem ^ (c&7)<<3)
    __shared__ float swl[64];

    const float* f2h_ = f2 + (size_t)h * N;
    for (int i = t; i < 6016; i += 256)
        f2s[i] = (i < N) ? f2h_[i] : 0.f;
    int nrow = n0 + r;
    float f1c = (nrow < N) ? f1[h * N + nrow] : 0.f;
    const u32* rbits = adjb + (size_t)nrow * NWORDS;   // OOB rows: garbage, store-guarded
    int xr = (r & 7) << 3;
    const u16* bsrc = WhbT + (size_t)h * HID * N;
    int c = t >> 1, sh = t & 1;
    int cx = (c & 7) << 3;
    __syncthreads();

    f32x4 acc[8];
#pragma unroll
    for (int ct = 0; ct < 8; ct++) acc[ct] = (f32x4){0.f, 0.f, 0.f, 0.f};
    float swp = 0.f;

    for (int ch = 0; ch < NCH; ch++) {
        int m0 = ch * 64;
        // ---- issue next Bt loads early (latency hidden under P-build)
        int mb = m0 + sh * 32;
        const u16* src = bsrc + (size_t)c * N + mb;
        uint4 v0, v1, v2, v3;
        if (mb + 32 <= N) {
            v0 = ((const uint4*)src)[0]; v1 = ((const uint4*)src)[1];
            v2 = ((const uint4*)src)[2]; v3 = ((const uint4*)src)[3];
        } else {
            u16 tmp[32];
#pragma unroll
            for (int j = 0; j < 32; j++) tmp[j] = (mb + j < N) ? src[j] : (u16)0;
            v0 = ((const uint4*)tmp)[0]; v1 = ((const uint4*)tmp)[1];
            v2 = ((const uint4*)tmp)[2]; v3 = ((const uint4*)tmp)[3];
        }
        // ---- dense P build: 16 elems per thread (row r, m = m0+16q+j)
        u32 bits = rbits[ch * 2 + (q >> 1)] >> ((q & 1) * 16);
        const float* fsrc = f2s + m0 + 16 * q;
        u32 pw[8];
#pragma unroll
        for (int jp = 0; jp < 8; jp++) {
            float s0 = f1c + fsrc[2 * jp];
            float s1 = f1c + fsrc[2 * jp + 1];
            float z0 = fmaxf(s0, 0.2f * s0);
            float z1 = fmaxf(s1, 0.2f * s1);
            float w0 = __expf(z0) * (float)((bits >> (2 * jp)) & 1);
            float w1 = __expf(z1) * (float)((bits >> (2 * jp + 1)) & 1);
            u32 b0 = f2bf(w0), b1 = f2bf(w1);
            swp += __uint_as_float(b0 << 16) + __uint_as_float(b1 << 16);
            pw[jp] = b0 | (b1 << 16);
        }
#pragma unroll
        for (int jp = 0; jp < 8; jp++)
            *(u32*)&P[r][(16 * q + 2 * jp) ^ xr] = pw[jp];
        // ---- land Bt
        *(uint4*)&Bt[c][(sh * 32 + 0)  ^ cx] = v0;
        *(uint4*)&Bt[c][(sh * 32 + 8)  ^ cx] = v1;
        *(uint4*)&Bt[c][(sh * 32 + 16) ^ cx] = v2;
        *(uint4*)&Bt[c][(sh * 32 + 24) ^ cx] = v3;
        __syncthreads();
        // ---- MFMA: 64 rows x 128 cols, k = 64 chunk
        int arow = 16 * wid + lr;
        int axr = (lr & 7) << 3;
#pragma unroll
        for (int ks = 0; ks < 2; ks++) {
            int kb = ks * 32 + 8 * l4;
            bf16x8 a = *(const bf16x8*)&P[arow][kb ^ axr];
#pragma unroll
            for (int ct = 0; ct < 8; ct++) {
                int brow = 16 * ct + lr;
                bf16x8 b = *(const bf16x8*)&Bt[brow][kb ^ ((brow & 7) << 3)];
                acc[ct] = __builtin_amdgcn_mfma_f32_16x16x32_bf16(a, b, acc[ct], 0, 0, 0);
            }
        }
        __syncthreads();
    }
    // row-sum reduce across the 4 q-threads (adjacent lanes)
    swp += __shfl_xor(swp, 1);
    swp += __shfl_xor(swp, 2);
    if (q == 0) swl[r] = swp;
    __syncthreads();
    // epilogue: C/D col = lane&15, row = 4*(lane>>4)+reg (HW-verified)
#pragma unroll
    for (int reg = 0; reg < 4; reg++) {
        int rl = 16 * wid + 4 * l4 + reg;
        int n = n0 + rl;
        if (n < N) {
            float inv = 1.f / swl[rl];
            u16* orow = hcatb + (size_t)n * (NH * HID) + h * HID;
#pragma unroll
            for (int ct = 0; ct < 8; ct++) {
                float v = acc[ct][reg] * inv;
                v = (v > 0.f) ? v : expm1f(v);
                orow[16 * ct + lr] = f2bf(v);
            }
        }
    }
}

// K4: partial = hcatb(6000x1024 bf16) @ WoT, MFMA 16x16x32, KSPLIT=4.
__global__ __launch_bounds__(256)
void gemm_out_mfma(const u16* __restrict__ hcatb,
                   const u16* __restrict__ WoT,
                   float* __restrict__ partial) {
    int n0 = blockIdx.x * 64;
    int ks = blockIdx.y;
    int t = threadIdx.x;
    int lane = t & 63, wid = t >> 6;
    int l4 = lane >> 4, lr = lane & 15;

    __shared__ u16 Bt[128][128];

    f32x4 acc[8];
#pragma unroll
    for (int ct = 0; ct < 8; ct++) acc[ct] = (f32x4){0.f, 0.f, 0.f, 0.f};

    int arow = n0 + 16 * wid + lr;
    const u16* asrc = hcatb + (size_t)arow * (NH * HID);
    bool avalid = (arow < N);

    for (int half = 0; half < 2; half++) {
        int kbeg = ks * 256 + half * 128;
        {
            int c = t >> 1, sh = t & 1;
            const u16* src = WoT + (size_t)c * 1024 + kbeg + sh * 64;
            int cx = (c & 7) << 3;
            uint4 v[8];
#pragma unroll
            for (int j = 0; j < 8; j++) v[j] = ((const uint4*)src)[j];
#pragma unroll
            for (int j = 0; j < 8; j++)
                *(uint4*)&Bt[c][(sh * 64 + 8 * j) ^ cx] = v[j];
        }
        __syncthreads();
#pragma unroll
        for (int kst = 0; kst < 4; kst++) {
            int kb = kst * 32 + 8 * l4;
            bf16x8 a = {0, 0, 0, 0, 0, 0, 0, 0};
            if (avalid) a = *(const bf16x8*)(asrc + kbeg + kb);
#pragma unroll
            for (int ct = 0; ct < 8; ct++) {
                int brow = 16 * ct + lr;
                bf16x8 b = *(const bf16x8*)&Bt[brow][kb ^ ((brow & 7) << 3)];
                acc[ct] = __builtin_amdgcn_mfma_f32_16x16x32_bf16(a, b, acc[ct], 0, 0, 0);
            }
        }
        __syncthreads();
    }
    float* pout = partial + (size_t)ks * N * HID;
#pragma unroll
    for (int reg = 0; reg < 4; reg++) {
        int n = n0 + 16 * wid + 4 * l4 + reg;
        if (n < N) {
#pragma unroll
            for (int ct = 0; ct < 8; ct++)
                pout[(size_t)n * HID + 16 * ct + lr] = acc[ct][reg];
        }
    }
}

// K4b: sum the KSPLIT partials -> fp16 Wh2h shadow; fused g1/g2 (fp32).
__global__ void reduce_wh2(const float* __restrict__ partial,
                           const float* __restrict__ a_out,
                           u16* __restrict__ Wh2h,
                           float* __restrict__ g1, float* __restrict__ g2) {
    int idx = blockIdx.x * 256 + threadIdx.x;
    float4 v = *(const float4*)(partial + 4 * (size_t)idx);
#pragma unroll
    for (int s = 1; s < KSPLIT; s++) {
        const float4 q = *(const float4*)(partial + (size_t)s * N * HID + 4 * (size_t)idx);
        v.x += q.x; v.y += q.y; v.z += q.z; v.w += q.w;
    }
    ushort4 h4;
    h4.x = f2h(v.x); h4.y = f2h(v.y); h4.z = f2h(v.z); h4.w = f2h(v.w);
    *(ushort4*)(Wh2h + 4 * (size_t)idx) = h4;

    int row = idx >> 5, cg = idx & 31;
    float p1 = v.x * a_out[4 * cg] + v.y * a_out[4 * cg + 1]
             + v.z * a_out[4 * cg + 2] + v.w * a_out[4 * cg + 3];
    float p2 = v.x * a_out[HID + 4 * cg] + v.y * a_out[HID + 4 * cg + 1]
             + v.z * a_out[HID + 4 * cg + 2] + v.w * a_out[HID + 4 * cg + 3];
    for (int d = 1; d <= 16; d <<= 1) { p1 += __shfl_xor(p1, d); p2 += __shfl_xor(p2, d); }
    if ((threadIdx.x & 31) == 0) { g1[row] = p1; g2[row] = p2; }
}

// K6: layer-2 fused masked-softmax + PV, fp16 gather (scalar, R15-verified).
__global__ void gat2(const u16* __restrict__ Wh2h,
                     const float* __restrict__ g1, const float* __restrict__ g2,
                     const u16* __restrict__ nbr,
                     const int* __restrict__ ncnt,
                     float* __restrict__ out) {
    int n = blockIdx.x, t = threadIdx.x;
    int s = t >> 4, op = t & 15;
    int cnt = ncnt[n];
    const u16* lst = nbr + (size_t)n * NBR_CAP;
    __shared__ float2 wm[NBR_CAP];
    __shared__ float accl[16][16][9];
    __shared__ float red4[4];

    float g1c = g1[n];
    float pw = 0.f;
    for (int i = t; i < cnt; i += 256) {
        int m = lst[i];
        float z = g1c + g2[m];
        z = (z >= 0.f) ? z : ALPHA * z;
        float wv = __expf(z);
        pw += wv;
        wm[i] = make_float2(wv, __uint_as_float((u32)m << 8));
    }
    for (int d = 1; d <= 32; d <<= 1) pw += __shfl_xor(pw, d);
    if ((t & 63) == 0) red4[t >> 6] = pw;
    __syncthreads();
    float swt = red4[0] + red4[1] + red4[2] + red4[3];

    const char* base = (const char*)Wh2h + (op << 4);
    float acc[8] = {};
    int j = s;
    for (; j + 16 < cnt; j += 32) {
        float2 p0 = wm[j];
        float2 p1 = wm[j + 16];
        const uint4 va = *(const uint4*)(base + __float_as_uint(p0.y));
        const uint4 vb = *(const uint4*)(base + __float_as_uint(p1.y));
        float w0 = p0.x, w1 = p1.x;
        acc[0] += w0 * __half2float(__ushort_as_half((u16)(va.x & 0xffff)));
        acc[1] += w0 * __half2float(__ushort_as_half((u16)(va.x >> 16)));
        acc[2] += w0 * __half2float(__ushort_as_half((u16)(va.y & 0xffff)));
        acc[3] += w0 * __half2float(__ushort_as_half((u16)(va.y >> 16)));
        acc[4] += w0 * __half2float(__ushort_as_half((u16)(va.z & 0xffff)));
        acc[5] += w0 * __half2float(__ushort_as_half((u16)(va.z >> 16)));
        acc[6] += w0 * __half2float(__ushort_as_half((u16)(va.w & 0xffff)));
        acc[7] += w0 * __half2float(__ushort_as_half((u16)(va.w >> 16)));
        acc[0] += w1 * __half2float(__ushort_as_half((u16)(vb.x & 0xffff)));
        acc[1] += w1 * __half2float(__ushort_as_half((u16)(vb.x >> 16)));
        acc[2] += w1 * __half2float(__ushort_as_half((u16)(vb.y & 0xffff)));
        acc[3] += w1 * __half2float(__ushort_as_half((u16)(vb.y >> 16)));
        acc[4] += w1 * __half2float(__ushort_as_half((u16)(vb.z & 0xffff)));
        acc[5] += w1 * __half2float(__ushort_as_half((u16)(vb.z >> 16)));
        acc[6] += w1 * __half2float(__ushort_as_half((u16)(vb.w & 0xffff)));
        acc[7] += w1 * __half2float(__ushort_as_half((u16)(vb.w >> 16)));
    }
    if (j < cnt) {
        float2 p0 = wm[j];
        const uint4 va = *(const uint4*)(base + __float_as_uint(p0.y));
        float w0 = p0.x;
        acc[0] += w0 * __half2float(__ushort_as_half((u16)(va.x & 0xffff)));
        acc[1] += w0 * __half2float(__ushort_as_half((u16)(va.x >> 16)));
        acc[2] += w0 * __half2float(__ushort_as_half((u16)(va.y & 0xffff)));
        acc[3] += w0 * __half2float(__ushort_as_half((u16)(va.y >> 16)));
        acc[4] += w0 * __half2float(__ushort_as_half((u16)(va.z & 0xffff)));
        acc[5] += w0 * __half2float(__ushort_as_half((u16)(va.z >> 16)));
        acc[6] += w0 * __half2float(__ushort_as_half((u16)(va.w & 0xffff)));
        acc[7] += w0 * __half2float(__ushort_as_half((u16)(va.w >> 16)));
    }
#pragma unroll
    for (int cc = 0; cc < 8; cc++) accl[s][op][cc] = acc[cc];
    __syncthreads();

    if (t < 128) {
        int cc = t;
        float r = 0.f;
#pragma unroll
        for (int k = 0; k < 16; k++) r += accl[k][cc >> 3][cc & 7];
        out[(size_t)n * HID + cc] = r / swt;
    }
}

extern "C" void kernel_launch(void* const* d_in, const int* in_sizes, int n_in,
                              void* d_out, int out_size, void* d_ws, size_t ws_size,
                              hipStream_t stream) {
    const float* x       = (const float*)d_in[0];
    const float* adj     = (const float*)d_in[1];
    const float* W_heads = (const float*)d_in[2];
    const float* a_heads = (const float*)d_in[3];
    const float* W_out   = (const float*)d_in[4];
    const float* a_out   = (const float*)d_in[5];
    float* out = (float*)d_out;

    char* wsb = (char*)d_ws;
    size_t off = 0;
    auto alloc = [&](size_t bytes) {
        void* p = wsb + off;
        off += (bytes + 255) & ~(size_t)255;
        return p;
    };
    float* partial = (float*)alloc(sizeof(float) * (size_t)KSPLIT * N * HID); // 12.3 MB
    u16*   WhbT = (u16*)  alloc(sizeof(u16)   * (size_t)NH * HID * N);        // 12.3 MB
    u16*   hcatb= (u16*)  alloc(sizeof(u16)   * (size_t)N * NH * HID);        // 12.3 MB
    u16*   xb   = (u16*)  alloc(sizeof(u16)   * (size_t)N * KPAD);            // 4.6 MB
    u16*   WbT  = (u16*)  alloc(sizeof(u16)   * (size_t)NH * HID * KPAD);     // 786 KB
    u16*   WoT  = (u16*)  alloc(sizeof(u16)   * (size_t)HID * 1024);          // 256 KB
    u16*   Wh2h = (u16*)  alloc(sizeof(u16)   * (size_t)N * HID);
    u32*   adjb = (u32*)  alloc(sizeof(u32)   * (size_t)N * NWORDS);          // 4.5 MB
    float* av1  = (float*)alloc(sizeof(float) * (size_t)NH * 320);
    float* av2  = (float*)alloc(sizeof(float) * (size_t)NH * 320);
    float* f1   = (float*)alloc(sizeof(float) * (size_t)NH * N);
    float* f2   = (float*)alloc(sizeof(float) * (size_t)NH * N);
    float* g1   = (float*)alloc(sizeof(float) * (size_t)N);
    float* g2   = (float*)alloc(sizeof(float) * (size_t)N);
    u16* nbr    = (u16*)  alloc(sizeof(u16)   * (size_t)N * NBR_CAP);
    int* ncnt   = (int*)  alloc(sizeof(int)   * (size_t)N);

    hipLaunchKernelGGL(prep_all, dim3(PREP_NBLK), dim3(256), 0, stream,
                       adj, x, W_heads, W_out, a_heads, nbr, ncnt, xb, WbT, WoT, av1, av2);
    hipLaunchKernelGGL(build_bitmask, dim3(N), dim3(256), 0, stream, nbr, ncnt, adjb);
    hipLaunchKernelGGL(calc_f, dim3(N), dim3(256), 0, stream, x, av1, av2, f1, f2);
    hipLaunchKernelGGL(gemm_whT_mfma, dim3((N + 63) / 64, NH), dim3(256), 0, stream,
                       xb, WbT, WhbT);
    hipLaunchKernelGGL(gat1_dense, dim3(NCH, NH), dim3(256), 0, stream,
                       WhbT, f1, f2, adjb, hcatb);
    hipLaunchKernelGGL(gemm_out_mfma, dim3((N + 63) / 64, KSPLIT), dim3(256), 0, stream,
                       hcatb, WoT, partial);
    hipLaunchKernelGGL(reduce_wh2, dim3(N * HID / 4 / 256), dim3(256), 0, stream,
                       partial, a_out, Wh2h, g1, g2);
    hipLaunchKernelGGL(gat2, dim3(N), dim3(256), 0, stream, Wh2h, g1, g2, nbr, ncnt, out);
}

// Round 18
// 278.859 us; speedup vs baseline: 1.2026x; 1.2026x over previous
//
#include <hip/hip_runtime.h>
#include <hip/hip_fp16.h>
#include <math.h>

#define N 6000
#define FIN 300
#define HID 128
#define NH 8
#define ALPHA 0.2f
#define NBR_CAP 512
#define KSPLIT 4
#define KPAD 384           // FIN padded to 3x128 for MFMA chunks

typedef unsigned short u16;
typedef unsigned int u32;
typedef short bf16x8 __attribute__((ext_vector_type(8)));
typedef float f32x4 __attribute__((ext_vector_type(4)));

static __device__ __forceinline__ u16 f2bf(float f) {
    u32 u = __float_as_uint(f);
    u32 r = (u + 0x7fff + ((u >> 16) & 1)) >> 16;   // round-to-nearest-even
    return (u16)r;
}
static __device__ __forceinline__ u16 f2h(float f) {
    return __half_as_ushort(__float2half(f));
}

// K0+K1 fused: blocks [0,6000) build neighbor lists; remaining blocks do
// bf16 prep (xb, WbT, WoT) and av GEMVs.
#define PREP_NBLK (6000 + 9000 + 1536 + 512 + 8)
__global__ void prep_all(const float* __restrict__ adj,
                         const float* __restrict__ x,
                         const float* __restrict__ W,
                         const float* __restrict__ W_out,
                         const float* __restrict__ a_heads,
                         u16* __restrict__ nbr, int* __restrict__ ncnt,
                         u16* __restrict__ xb,
                         u16* __restrict__ WbT,
                         u16* __restrict__ WoT,
                         float* __restrict__ av1, float* __restrict__ av2) {
    int bid = blockIdx.x, t = threadIdx.x;
    __shared__ u16 lbuf[4][256];
    __shared__ int wc[4];
    __shared__ float a1s[HID], a2s[HID];
    if (bid < 6000) {                       // ---- build_nbr
        int n = bid;
        int lane = t & 63, w = t >> 6;
        const int seg = N / 4;              // 1500
        int start = w * seg, end = start + seg;
        const float* row = adj + (size_t)n * N;
        int cnt = 0;
        for (int base = start; base < end; base += 256) {
            int m0 = base + 4 * lane;
            float4 v = make_float4(0.f, 0.f, 0.f, 0.f);
            if (m0 < end) v = *(const float4*)(row + m0);
#pragma unroll
            for (int c = 0; c < 4; c++) {
                float vc = (c == 0) ? v.x : (c == 1) ? v.y : (c == 2) ? v.z : v.w;
                bool p = vc > 0.5f;
                unsigned long long mask = __ballot(p);
                if (p) {
                    int pos = cnt + __popcll(mask & ((1ull << lane) - 1ull));
                    if (pos < 256) lbuf[w][pos] = (u16)(m0 + c);
                }
                cnt += __popcll(mask);
            }
        }
        if (cnt > 256) cnt = 256;
        if (lane == 0) wc[w] = cnt;
        __syncthreads();
        int offset = 0;
        for (int i = 0; i < w; i++) offset += wc[i];
        for (int i = lane; i < cnt; i += 64) {
            int idx = offset + i;
            if (idx < NBR_CAP) nbr[(size_t)n * NBR_CAP + idx] = lbuf[w][i];
        }
        if (t == 0) {
            int total = wc[0] + wc[1] + wc[2] + wc[3];
            ncnt[n] = total < NBR_CAP ? total : NBR_CAP;
        }
    } else if (bid < 6000 + 9000) {         // xb[n][k], 6000x384
        int idx = (bid - 6000) * 256 + t;
        int n = idx / KPAD, k = idx - n * KPAD;
        xb[idx] = (k < FIN) ? f2bf(x[(size_t)n * FIN + k]) : (u16)0;
    } else if (bid < 6000 + 9000 + 1536) {  // WbT[h][c][k], 8x128x384
        int idx = (bid - 6000 - 9000) * 256 + t;
        int k = idx % KPAD;
        int c = (idx / KPAD) & 127;
        int h = idx / (KPAD * HID);
        WbT[idx] = (k < FIN) ? f2bf(W[((size_t)h * FIN + k) * HID + c]) : (u16)0;
    } else if (bid < 6000 + 9000 + 1536 + 512) {   // WoT[c][k], 128x1024
        int idx = (bid - 6000 - 9000 - 1536) * 256 + t;
        int k = idx & 1023, c = idx >> 10;
        WoT[idx] = f2bf(W_out[(size_t)k * HID + c]);
    } else {                                // av1/av2[h][0..320)
        int h = bid - (6000 + 9000 + 1536 + 512);
        if (t < HID) {
            a1s[t] = a_heads[(size_t)h * 2 * HID + t];
            a2s[t] = a_heads[(size_t)h * 2 * HID + HID + t];
        }
        __syncthreads();
        for (int f = t; f < 320; f += 256) {
            float s1 = 0.f, s2 = 0.f;
            if (f < FIN) {
                const float* wr = W + ((size_t)h * FIN + f) * HID;
#pragma unroll 4
                for (int o = 0; o < HID; o++) { s1 += wr[o] * a1s[o]; s2 += wr[o] * a2s[o]; }
            }
            av1[h * 320 + f] = s1;
            av2[h * 320 + f] = s2;
        }
    }
}

// K2: f1[h][n] = x[n]·av1[h], f2 likewise — fp32-exact logits.
__global__ void calc_f(const float* __restrict__ x,
                       const float* __restrict__ av1, const float* __restrict__ av2,
                       float* __restrict__ f1, float* __restrict__ f2) {
    int n = blockIdx.x, t = threadIdx.x;
    int lane = t & 63, w = t >> 6;
    __shared__ float xsh[320];
    for (int i = t; i < 320; i += 256)
        xsh[i] = (i < FIN) ? x[(size_t)n * FIN + i] : 0.f;
    __syncthreads();
#pragma unroll
    for (int hh = 0; hh < 2; hh++) {
        int h = 2 * w + hh;
        const float* a1 = av1 + h * 320;
        const float* a2 = av2 + h * 320;
        float s1 = 0.f, s2 = 0.f;
#pragma unroll
        for (int i = 0; i < 5; i++) {
            float xv = xsh[lane + 64 * i];
            s1 += xv * a1[lane + 64 * i];
            s2 += xv * a2[lane + 64 * i];
        }
        for (int d = 1; d <= 32; d <<= 1) { s1 += __shfl_xor(s1, d); s2 += __shfl_xor(s2, d); }
        if (lane == 0) { f1[h * N + n] = s1; f2[h * N + n] = s2; }
    }
}

// K3a: Whb[h][n][c] = bf16( xb @ WbT[h] ), MFMA 16x16x32, K=384 in 3 chunks.
__global__ __launch_bounds__(256)
void gemm_wh_mfma(const u16* __restrict__ xb,
                  const u16* __restrict__ WbT,
                  u16* __restrict__ Whb) {
    int n0 = blockIdx.x * 64;
    int h = blockIdx.y;
    int t = threadIdx.x;
    int lane = t & 63, wid = t >> 6;
    int l4 = lane >> 4, lr = lane & 15;

    __shared__ u16 Bt[128][128];         // 32 KB, swizzled

    f32x4 acc[8];
#pragma unroll
    for (int ct = 0; ct < 8; ct++) acc[ct] = (f32x4){0.f, 0.f, 0.f, 0.f};

    int arow = n0 + 16 * wid + lr;
    const u16* asrc = xb + (size_t)arow * KPAD;
    bool avalid = (arow < N);

    for (int half = 0; half < 3; half++) {
        int kbeg = half * 128;
        {
            int c = t >> 1, sh = t & 1;
            const u16* src = WbT + ((size_t)h * HID + c) * KPAD + kbeg + sh * 64;
            int cx = (c & 7) << 3;
            uint4 v[8];
#pragma unroll
            for (int j = 0; j < 8; j++) v[j] = ((const uint4*)src)[j];
#pragma unroll
            for (int j = 0; j < 8; j++)
                *(uint4*)&Bt[c][(sh * 64 + 8 * j) ^ cx] = v[j];
        }
        __syncthreads();
#pragma unroll
        for (int kst = 0; kst < 4; kst++) {
            int kb = kst * 32 + 8 * l4;
            bf16x8 a = {0, 0, 0, 0, 0, 0, 0, 0};
            if (avalid) a = *(const bf16x8*)(asrc + kbeg + kb);
#pragma unroll
            for (int ct = 0; ct < 8; ct++) {
                int brow = 16 * ct + lr;
                bf16x8 b = *(const bf16x8*)&Bt[brow][kb ^ ((brow & 7) << 3)];
                acc[ct] = __builtin_amdgcn_mfma_f32_16x16x32_bf16(a, b, acc[ct], 0, 0, 0);
            }
        }
        __syncthreads();
    }
#pragma unroll
    for (int reg = 0; reg < 4; reg++) {
        int n = n0 + 16 * wid + 4 * l4 + reg;
        if (n < N) {
            u16* orow = Whb + ((size_t)h * N + n) * HID;
#pragma unroll
            for (int ct = 0; ct < 8; ct++)
                orow[16 * ct + lr] = f2bf(acc[ct][reg]);
        }
    }
}

// K3: layer-1 fused masked-softmax + PV; sw hoisted into phase A.
__global__ void gat1(const u16* __restrict__ Whb,
                     const float* __restrict__ f1, const float* __restrict__ f2,
                     const u16* __restrict__ nbr,
                     const int* __restrict__ ncnt,
                     u16* __restrict__ hcatb) {
    int bid = blockIdx.x;
    int h = bid / N, n = bid - h * N;
    int t = threadIdx.x;
    int s = t >> 4, op = t & 15;
    int cnt = ncnt[n];
    const u16* lst = nbr + (size_t)n * NBR_CAP;
    __shared__ float2 wm[NBR_CAP];        // {weight, byte-offset bits}
    __shared__ float accl[16][16][9];     // padded
    __shared__ float red4[4];

    float f1c = f1[h * N + n];
    float pw = 0.f;
    for (int i = t; i < cnt; i += 256) {
        int m = lst[i];
        float z = f1c + f2[h * N + m];
        z = (z >= 0.f) ? z : ALPHA * z;
        float wv = __expf(z);
        pw += wv;
        wm[i] = make_float2(wv, __uint_as_float((u32)m << 8));
    }
    for (int d = 1; d <= 32; d <<= 1) pw += __shfl_xor(pw, d);
    if ((t & 63) == 0) red4[t >> 6] = pw;
    __syncthreads();
    float swt = red4[0] + red4[1] + red4[2] + red4[3];

    const char* base = (const char*)(Whb + (size_t)h * N * HID) + (op << 4);
    float acc[8] = {};
    int j = s;
    for (; j + 16 < cnt; j += 32) {
        float2 p0 = wm[j];
        float2 p1 = wm[j + 16];
        const uint4 va = *(const uint4*)(base + __float_as_uint(p0.y));
        const uint4 vb = *(const uint4*)(base + __float_as_uint(p1.y));
        float w0 = p0.x, w1 = p1.x;
        acc[0] += w0 * __uint_as_float(va.x << 16);
        acc[1] += w0 * __uint_as_float(va.x);
        acc[2] += w0 * __uint_as_float(va.y << 16);
        acc[3] += w0 * __uint_as_float(va.y);
        acc[4] += w0 * __uint_as_float(va.z << 16);
        acc[5] += w0 * __uint_as_float(va.z);
        acc[6] += w0 * __uint_as_float(va.w << 16);
        acc[7] += w0 * __uint_as_float(va.w);
        acc[0] += w1 * __uint_as_float(vb.x << 16);
        acc[1] += w1 * __uint_as_float(vb.x);
        acc[2] += w1 * __uint_as_float(vb.y << 16);
        acc[3] += w1 * __uint_as_float(vb.y);
        acc[4] += w1 * __uint_as_float(vb.z << 16);
        acc[5] += w1 * __uint_as_float(vb.z);
        acc[6] += w1 * __uint_as_float(vb.w << 16);
        acc[7] += w1 * __uint_as_float(vb.w);
    }
    if (j < cnt) {
        float2 p0 = wm[j];
        const uint4 va = *(const uint4*)(base + __float_as_uint(p0.y));
        float w0 = p0.x;
        acc[0] += w0 * __uint_as_float(va.x << 16);
        acc[1] += w0 * __uint_as_float(va.x);
        acc[2] += w0 * __uint_as_float(va.y << 16);
        acc[3] += w0 * __uint_as_float(va.y);
        acc[4] += w0 * __uint_as_float(va.z << 16);
        acc[5] += w0 * __uint_as_float(va.z);
        acc[6] += w0 * __uint_as_float(va.w << 16);
        acc[7] += w0 * __uint_as_float(va.w);
    }
#pragma unroll
    for (int c = 0; c < 8; c++) accl[s][op][c] = acc[c];
    __syncthreads();

    if (t < 128) {
        int c = t;
        float r = 0.f;
#pragma unroll
        for (int k = 0; k < 16; k++) r += accl[k][c >> 3][c & 7];
        r /= swt;
        r = (r > 0.f) ? r : expm1f(r);
        hcatb[(size_t)n * (NH * HID) + h * HID + c] = f2bf(r);
    }
}

// K4: partial = hcatb(6000x1024 bf16) @ WoT, MFMA 16x16x32, KSPLIT=4.
__global__ __launch_bounds__(256)
void gemm_out_mfma(const u16* __restrict__ hcatb,
                   const u16* __restrict__ WoT,
                   float* __restrict__ partial) {
    int n0 = blockIdx.x * 64;
    int ks = blockIdx.y;                 // K slice of 256
    int t = threadIdx.x;
    int lane = t & 63, wid = t >> 6;
    int l4 = lane >> 4, lr = lane & 15;

    __shared__ u16 Bt[128][128];         // 32 KB, swizzled

    f32x4 acc[8];
#pragma unroll
    for (int ct = 0; ct < 8; ct++) acc[ct] = (f32x4){0.f, 0.f, 0.f, 0.f};

    int arow = n0 + 16 * wid + lr;
    const u16* asrc = hcatb + (size_t)arow * (NH * HID);
    bool avalid = (arow < N);

    for (int half = 0; half < 2; half++) {
        int kbeg = ks * 256 + half * 128;
        {
            int c = t >> 1, sh = t & 1;
            const u16* src = WoT + (size_t)c * 1024 + kbeg + sh * 64;
            int cx = (c & 7) << 3;
            uint4 v[8];
#pragma unroll
            for (int j = 0; j < 8; j++) v[j] = ((const uint4*)src)[j];
#pragma unroll
            for (int j = 0; j < 8; j++)
                *(uint4*)&Bt[c][(sh * 64 + 8 * j) ^ cx] = v[j];
        }
        __syncthreads();
#pragma unroll
        for (int kst = 0; kst < 4; kst++) {
            int kb = kst * 32 + 8 * l4;
            bf16x8 a = {0, 0, 0, 0, 0, 0, 0, 0};
            if (avalid) a = *(const bf16x8*)(asrc + kbeg + kb);
#pragma unroll
            for (int ct = 0; ct < 8; ct++) {
                int brow = 16 * ct + lr;
                bf16x8 b = *(const bf16x8*)&Bt[brow][kb ^ ((brow & 7) << 3)];
                acc[ct] = __builtin_amdgcn_mfma_f32_16x16x32_bf16(a, b, acc[ct], 0, 0, 0);
            }
        }
        __syncthreads();
    }
    float* pout = partial + (size_t)ks * N * HID;
#pragma unroll
    for (int reg = 0; reg < 4; reg++) {
        int n = n0 + 16 * wid + 4 * l4 + reg;
        if (n < N) {
#pragma unroll
            for (int ct = 0; ct < 8; ct++)
                pout[(size_t)n * HID + 16 * ct + lr] = acc[ct][reg];
        }
    }
}

// K4b: sum the KSPLIT partials -> fp16 Wh2h shadow; fused g1/g2 (fp32).
__global__ void reduce_wh2(const float* __restrict__ partial,
                           const float* __restrict__ a_out,
                           u16* __restrict__ Wh2h,
                           float* __restrict__ g1, float* __restrict__ g2) {
    int idx = blockIdx.x * 256 + threadIdx.x;      // float4 index
    float4 v = *(const float4*)(partial + 4 * (size_t)idx);
#pragma unroll
    for (int s = 1; s < KSPLIT; s++) {
        const float4 q = *(const float4*)(partial + (size_t)s * N * HID + 4 * (size_t)idx);
        v.x += q.x; v.y += q.y; v.z += q.z; v.w += q.w;
    }
    ushort4 h4;
    h4.x = f2h(v.x); h4.y = f2h(v.y); h4.z = f2h(v.z); h4.w = f2h(v.w);
    *(ushort4*)(Wh2h + 4 * (size_t)idx) = h4;

    int row = idx >> 5, cg = idx & 31;
    float p1 = v.x * a_out[4 * cg] + v.y * a_out[4 * cg + 1]
             + v.z * a_out[4 * cg + 2] + v.w * a_out[4 * cg + 3];
    float p2 = v.x * a_out[HID + 4 * cg] + v.y * a_out[HID + 4 * cg + 1]
             + v.z * a_out[HID + 4 * cg + 2] + v.w * a_out[HID + 4 * cg + 3];
    for (int d = 1; d <= 16; d <<= 1) { p1 += __shfl_xor(p1, d); p2 += __shfl_xor(p2, d); }
    if ((threadIdx.x & 31) == 0) { g1[row] = p1; g2[row] = p2; }
}

// K6: layer-2 fused masked-softmax + PV, fp16 gather; sw hoisted like gat1.
__global__ void gat2(const u16* __restrict__ Wh2h,
                     const float* __restrict__ g1, const float* __restrict__ g2,
                     const u16* __restrict__ nbr,
                     const int* __restrict__ ncnt,
                     float* __restrict__ out) {
    int n = blockIdx.x, t = threadIdx.x;
    int s = t >> 4, op = t & 15;
    int cnt = ncnt[n];
    const u16* lst = nbr + (size_t)n * NBR_CAP;
    __shared__ float2 wm[NBR_CAP];
    __shared__ float accl[16][16][9];
    __shared__ float red4[4];

    float g1c = g1[n];
    float pw = 0.f;
    for (int i = t; i < cnt; i += 256) {
        int m = lst[i];
        float z = g1c + g2[m];
        z = (z >= 0.f) ? z : ALPHA * z;
        float wv = __expf(z);
        pw += wv;
        wm[i] = make_float2(wv, __uint_as_float((u32)m << 8));
    }
    for (int d = 1; d <= 32; d <<= 1) pw += __shfl_xor(pw, d);
    if ((t & 63) == 0) red4[t >> 6] = pw;
    __syncthreads();
    float swt = red4[0] + red4[1] + red4[2] + red4[3];

    const char* base = (const char*)Wh2h + (op << 4);
    float acc[8] = {};
    int j = s;
    for (; j + 16 < cnt; j += 32) {
        float2 p0 = wm[j];
        float2 p1 = wm[j + 16];
        const uint4 va = *(const uint4*)(base + __float_as_uint(p0.y));
        const uint4 vb = *(const uint4*)(base + __float_as_uint(p1.y));
        float w0 = p0.x, w1 = p1.x;
        acc[0] += w0 * __half2float(__ushort_as_half((u16)(va.x & 0xffff)));
        acc[1] += w0 * __half2float(__ushort_as_half((u16)(va.x >> 16)));
        acc[2] += w0 * __half2float(__ushort_as_half((u16)(va.y & 0xffff)));
        acc[3] += w0 * __half2float(__ushort_as_half((u16)(va.y >> 16)));
        acc[4] += w0 * __half2float(__ushort_as_half((u16)(va.z & 0xffff)));
        acc[5] += w0 * __half2float(__ushort_as_half((u16)(va.z >> 16)));
        acc[6] += w0 * __half2float(__ushort_as_half((u16)(va.w & 0xffff)));
        acc[7] += w0 * __half2float(__ushort_as_half((u16)(va.w >> 16)));
        acc[0] += w1 * __half2float(__ushort_as_half((u16)(vb.x & 0xffff)));
        acc[1] += w1 * __half2float(__ushort_as_half((u16)(vb.x >> 16)));
        acc[2] += w1 * __half2float(__ushort_as_half((u16)(vb.y & 0xffff)));
        acc[3] += w1 * __half2float(__ushort_as_half((u16)(vb.y >> 16)));
        acc[4] += w1 * __half2float(__ushort_as_half((u16)(vb.z & 0xffff)));
        acc[5] += w1 * __half2float(__ushort_as_half((u16)(vb.z >> 16)));
        acc[6] += w1 * __half2float(__ushort_as_half((u16)(vb.w & 0xffff)));
        acc[7] += w1 * __half2float(__ushort_as_half((u16)(vb.w >> 16)));
    }
    if (j < cnt) {
        float2 p0 = wm[j];
        const uint4 va = *(const uint4*)(base + __float_as_uint(p0.y));
        float w0 = p0.x;
        acc[0] += w0 * __half2float(__ushort_as_half((u16)(va.x & 0xffff)));
        acc[1] += w0 * __half2float(__ushort_as_half((u16)(va.x >> 16)));
        acc[2] += w0 * __half2float(__ushort_as_half((u16)(va.y & 0xffff)));
        acc[3] += w0 * __half2float(__ushort_as_half((u16)(va.y >> 16)));
        acc[4] += w0 * __half2float(__ushort_as_half((u16)(va.z & 0xffff)));
        acc[5] += w0 * __half2float(__ushort_as_half((u16)(va.z >> 16)));
        acc[6] += w0 * __half2float(__ushort_as_half((u16)(va.w & 0xffff)));
        acc[7] += w0 * __half2float(__ushort_as_half((u16)(va.w >> 16)));
    }
#pragma unroll
    for (int c = 0; c < 8; c++) accl[s][op][c] = acc[c];
    __syncthreads();

    if (t < 128) {
        int c = t;
        float r = 0.f;
#pragma unroll
        for (int k = 0; k < 16; k++) r += accl[k][c >> 3][c & 7];
        out[(size_t)n * HID + c] = r / swt;
    }
}

extern "C" void kernel_launch(void* const* d_in, const int* in_sizes, int n_in,
                              void* d_out, int out_size, void* d_ws, size_t ws_size,
                              hipStream_t stream) {
    const float* x       = (const float*)d_in[0];
    const float* adj     = (const float*)d_in[1];
    const float* W_heads = (const float*)d_in[2];
    const float* a_heads = (const float*)d_in[3];
    const float* W_out   = (const float*)d_in[4];
    const float* a_out   = (const float*)d_in[5];
    float* out = (float*)d_out;

    char* wsb = (char*)d_ws;
    size_t off = 0;
    auto alloc = [&](size_t bytes) {
        void* p = wsb + off;
        off += (bytes + 255) & ~(size_t)255;
        return p;
    };
    float* partial = (float*)alloc(sizeof(float) * (size_t)KSPLIT * N * HID); // 12.3 MB
    u16*   Whb  = (u16*)  alloc(sizeof(u16)   * (size_t)NH * N * HID);        // 12.3 MB
    u16*   hcatb= (u16*)  alloc(sizeof(u16)   * (size_t)N * NH * HID);        // 12.3 MB
    u16*   xb   = (u16*)  alloc(sizeof(u16)   * (size_t)N * KPAD);            // 4.6 MB
    u16*   WbT  = (u16*)  alloc(sizeof(u16)   * (size_t)NH * HID * KPAD);     // 786 KB
    u16*   WoT  = (u16*)  alloc(sizeof(u16)   * (size_t)HID * 1024);          // 256 KB
    u16*   Wh2h = (u16*)  alloc(sizeof(u16)   * (size_t)N * HID);
    float* av1  = (float*)alloc(sizeof(float) * (size_t)NH * 320);
    float* av2  = (float*)alloc(sizeof(float) * (size_t)NH * 320);
    float* f1   = (float*)alloc(sizeof(float) * (size_t)NH * N);
    float* f2   = (float*)alloc(sizeof(float) * (size_t)NH * N);
    float* g1   = (float*)alloc(sizeof(float) * (size_t)N);
    float* g2   = (float*)alloc(sizeof(float) * (size_t)N);
    u16* nbr    = (u16*)  alloc(sizeof(u16)   * (size_t)N * NBR_CAP);
    int* ncnt   = (int*)  alloc(sizeof(int)   * (size_t)N);

    hipLaunchKernelGGL(prep_all, dim3(PREP_NBLK), dim3(256), 0, stream,
                       adj, x, W_heads, W_out, a_heads, nbr, ncnt, xb, WbT, WoT, av1, av2);
    hipLaunchKernelGGL(calc_f, dim3(N), dim3(256), 0, stream, x, av1, av2, f1, f2);
    hipLaunchKernelGGL(gemm_wh_mfma, dim3((N + 63) / 64, NH), dim3(256), 0, stream,
                       xb, WbT, Whb);
    hipLaunchKernelGGL(gat1, dim3(NH * N), dim3(256), 0, stream, Whb, f1, f2, nbr, ncnt, hcatb);
    hipLaunchKernelGGL(gemm_out_mfma, dim3((N + 63) / 64, KSPLIT), dim3(256), 0, stream,
                       hcatb, WoT, partial);
    hipLaunchKernelGGL(reduce_wh2, dim3(N * HID / 4 / 256), dim3(256), 0, stream,
                       partial, a_out, Wh2h, g1, g2);
    hipLaunchKernelGGL(gat2, dim3(N), dim3(256), 0, stream, Wh2h, g1, g2, nbr, ncnt, out);
}